// Round 3
// baseline (511.497 us; speedup 1.0000x reference)
//
#include <hip/hip_runtime.h>

// LSS voxel pooling: N_POINTS=692736, C=64, B=4, NX=256, NY=256, NZ=1 (gz==0)
// final[b, c, 0, ix, iy] = sum over points at (ix,iy,b) of x[:, c]
// out flat: ((b*64 + c)*256 + ix)*256 + iy   (fp32, 64 MB)
//
// Strategy v4: bucketing + COOPERATIVE COALESCED gather.
//   v3 post-mortem: gather was latency-bound (2.1 TB/s, occ 39%) because each
//   thread read a random 256 B x-row as 16 serial 16 B loads. v4 reads every
//   row with a 16-lane group (float4/lane = 256 B coalesced), accumulates in
//   LDS with ds-atomics, and writes out in 256 B bursts. 4096 blocks, ~87% occ.

#define NPTS   692736          // = 2706 * 256 exactly
#define CFEAT  64
#define NXV    256
#define NYV    256
#define NBAT   4
#define NVOX   (NBAT * NXV * NYV)   // 262144
#define CAP    16                   // slots per voxel; P(count>16) ~ 2e-8
#define BLKV   64                   // voxels per gather block
#define MAXP   (BLKV * CAP)         // 1024 worklist entries max (bucket part)

typedef float f32x4 __attribute__((ext_vector_type(4)));

// ws layout (bytes):
//   [0,      1 MB)   count   (memset to 0 each call)
//   [1 MB,   +4 B)   ovf_cnt (memset to 0, same memset)
//   [1 MB+64,8 MB)   ovf pairs (v, i) — worst case NPTS entries = 5.5 MB, fits
//   [8 MB,  24 MB)   bucket[CAP][NVOX]

__device__ __forceinline__ int voxel_of(const int* __restrict__ geom, int i) {
    const int4 g = *(const int4*)(geom + (size_t)i * 4);   // gx, gy, gz(=0), gb
    return (g.w * NXV + g.x) * NYV + g.y;
}

// --- 1: bin point indices into fixed-capacity per-voxel buckets -------------
__global__ __launch_bounds__(256) void fill_kernel(
    const int* __restrict__ geom, int* __restrict__ count,
    int* __restrict__ bucket, int* __restrict__ ovf_cnt, int* __restrict__ ovf)
{
    int i = blockIdx.x * 256 + threadIdx.x;     // grid exact: 2706*256 == NPTS
    int v = voxel_of(geom, i);
    int pos = atomicAdd(&count[v], 1);
    if (pos < CAP) {
        // transposed layout + nontemporal: no write-allocate RMW in L2
        __builtin_nontemporal_store(i, bucket + (size_t)pos * NVOX + v);
    } else {                                    // essentially never taken
        int j = atomicAdd(ovf_cnt, 1);
        ovf[2 * j]     = v;
        ovf[2 * j + 1] = i;
    }
}

// --- 2: cooperative gather-sum --------------------------------------------
// Block = 64 consecutive voxels (fixed b, ix; iy0..iy0+63). 256 threads.
__global__ __launch_bounds__(256) void gather_kernel(
    const float* __restrict__ x, const int* __restrict__ count,
    const int* __restrict__ bucket, const int* __restrict__ ovf_cnt,
    const int* __restrict__ ovf, float* __restrict__ out)
{
    __shared__ float acc[BLKV][CFEAT + 1];      // +1 pad: conflict-free readout
    __shared__ int   plist[MAXP];
    __shared__ unsigned char pslot[MAXP];
    __shared__ int   npts;

    const int tid   = threadIdx.x;
    const int vbase = blockIdx.x * BLKV;

    // zero accumulators
    for (int t = tid; t < BLKV * (CFEAT + 1); t += 256)
        ((float*)acc)[t] = 0.f;
    if (tid == 0) npts = 0;
    __syncthreads();

    // phase 1: wave 0 builds the worklist (coalesced count/bucket reads)
    if (tid < BLKV) {
        int v   = vbase + tid;
        int cnt = count[v];
        int n   = cnt < CAP ? cnt : CAP;
        for (int k = 0; k < n; ++k) {
            int p   = bucket[(size_t)k * NVOX + v];
            int pos = atomicAdd(&npts, 1);
            plist[pos] = p;
            pslot[pos] = (unsigned char)tid;
        }
        if (cnt > CAP) {               // correctness path; never in practice
            int no = *ovf_cnt;
            for (int j = 0; j < no; ++j) {
                if (ovf[2 * j] == v) {
                    const float* row = x + (size_t)ovf[2 * j + 1] * CFEAT;
                    for (int c = 0; c < CFEAT; ++c)
                        atomicAdd(&acc[tid][c], row[c]);
                }
            }
        }
    }
    __syncthreads();

    // phase 2: drain worklist; 16-lane group reads one 256 B row coalesced
    const int n      = npts;
    const int lane16 = tid & 15;
    const int group  = tid >> 4;                 // 16 groups of 16 lanes
    for (int j = group; j < n; j += 16) {
        int p    = plist[j];
        int slot = pslot[j];
        f32x4 f  = __builtin_nontemporal_load(
                       (const f32x4*)(x + (size_t)p * CFEAT) + lane16);
        float* a = &acc[slot][lane16 * 4];
        atomicAdd(a + 0, f.x);
        atomicAdd(a + 1, f.y);
        atomicAdd(a + 2, f.z);
        atomicAdd(a + 3, f.w);
    }
    __syncthreads();

    // phase 3: write out[b, c, ix, iy0..iy0+63] — 256 B burst per wave-instr
    const int b   = vbase >> 16;
    const int ix  = (vbase >> 8) & 255;
    const int iy0 = vbase & 255;                 // multiple of BLKV
    const int cpart = tid >> 6;                  // wave id: 0..3
    const int iyl   = tid & 63;
    size_t base = ((size_t)b * CFEAT) * (NXV * NYV)
                + (size_t)ix * NYV + iy0 + iyl;
    #pragma unroll
    for (int cc = 0; cc < CFEAT; cc += 4) {
        int c = cc + cpart;
        __builtin_nontemporal_store(acc[iyl][c],
            out + base + (size_t)c * (NXV * NYV));
    }
}

extern "C" void kernel_launch(void* const* d_in, const int* in_sizes, int n_in,
                              void* d_out, int out_size, void* d_ws, size_t ws_size,
                              hipStream_t stream) {
    const float* x  = (const float*)d_in[0];   // fp32 [NPTS,64]
    const int* geom = (const int*)d_in[1];     // [NPTS,4]
    float* out      = (float*)d_out;           // fp32 [4,64,256,256]

    char* w = (char*)d_ws;
    int* count   = (int*)(w);
    int* ovf_cnt = (int*)(w + (1u << 20));
    int* ovf     = (int*)(w + (1u << 20) + 64);
    int* bucket  = (int*)(w + (8u << 20));

    // zero count + ovf_cnt in one memset
    hipMemsetAsync(w, 0, (1u << 20) + 64, stream);

    fill_kernel  <<<NPTS / 256, 256, 0, stream>>>(geom, count, bucket, ovf_cnt, ovf);
    gather_kernel<<<NVOX / BLKV, 256, 0, stream>>>(x, count, bucket, ovf_cnt, ovf, out);
}

// Round 4
// 421.179 us; speedup vs baseline: 1.2144x; 1.2144x over previous
//
#include <hip/hip_runtime.h>

// LSS voxel pooling: N_POINTS=692736, C=64, B=4, NX=256, NY=256, NZ=1 (gz==0)
// final[b, c, 0, ix, iy] = sum over points at (ix,iy,b) of x[:, c]
// out flat: ((b*64 + c)*256 + ix)*256 + iy   (fp32, 64 MB)
//
// Strategy v5: fixed-capacity bucket[v][8] + FIXED-TRIP PREDICATED gather.
//   v2/v3/v4 post-mortem: all latency-bound (VALUBusy ~2%, <=2.1 TB/s).
//   Root cause: runtime-trip k-loop with a dependent idx load per iteration
//   -> compiler can't pipeline -> ~8 loads in flight per thread.
//   v5: thread loads ALL 8 slot ids with two independent int4 loads, then
//   issues 8x8 independent predicated float4 loads (compile-time unroll).
//   One dependency level; ~20 KB in flight per wave.
//   CAP=8: P(cnt>8)=0.19% -> overflow list, slow path touches ~500 threads.

#define NPTS   692736          // = 2706 * 256 exactly
#define CFEAT  64
#define NXV    256
#define NYV    256
#define NBAT   4
#define NVOX   (NBAT * NXV * NYV)   // 262144
#define CAP    8                    // slots per voxel; P(cnt>8) ~ 0.19%

typedef float f32x4 __attribute__((ext_vector_type(4)));

// ws layout (bytes):
//   [0,      1 MB)   count   (memset to 0 each call)
//   [1 MB,   +4 B)   ovf_cnt (memset to 0, same memset)
//   [1 MB+64,8 MB)   ovf pairs (v, i) — worst case NPTS entries = 5.5 MB, fits
//   [8 MB,  16 MB)   bucket[NVOX][CAP]

__device__ __forceinline__ int voxel_of(const int* __restrict__ geom, int i) {
    const int4 g = *(const int4*)(geom + (size_t)i * 4);   // gx, gy, gz(=0), gb
    return (g.w * NXV + g.x) * NYV + g.y;
}

// --- 1: bin point indices into fixed-capacity per-voxel buckets -------------
__global__ __launch_bounds__(256) void fill_kernel(
    const int* __restrict__ geom, int* __restrict__ count,
    int* __restrict__ bucket, int* __restrict__ ovf_cnt, int* __restrict__ ovf)
{
    int i = blockIdx.x * 256 + threadIdx.x;     // grid exact: 2706*256 == NPTS
    int v = voxel_of(geom, i);
    int pos = atomicAdd(&count[v], 1);
    if (pos < CAP) {
        bucket[(size_t)v * CAP + pos] = i;      // L2-resident; gather reads next
    } else {                                    // 0.19% of voxels
        int j = atomicAdd(ovf_cnt, 1);
        ovf[2 * j]     = v;
        ovf[2 * j + 1] = i;
    }
}

// --- 2: gather-sum, write directly in [B, C, X, Y] --------------------------
// 256 threads = 128 consecutive voxels x 2 channel-halves (h = tid>>7).
// Per thread: count + 2x int4 bucket loads (independent, coalesced), then
// 8 predicated unrolled rows x 8 float4 loads — all addresses known after
// one dependency level, so the MLP is ~cnt*128 B per thread.
__global__ __launch_bounds__(256) void gather_kernel(
    const float* __restrict__ x, const int* __restrict__ count,
    const int* __restrict__ bucket, const int* __restrict__ ovf_cnt,
    const int* __restrict__ ovf, float* __restrict__ out)
{
    const int h  = threadIdx.x >> 7;            // channel half: [h*32, h*32+32)
    const int v  = blockIdx.x * 128 + (threadIdx.x & 127);

    const int cnt = count[v];
    const int4 b0 = *((const int4*)(bucket + (size_t)v * CAP));
    const int4 b1 = *((const int4*)(bucket + (size_t)v * CAP) + 1);
    const int pa[8] = { b0.x, b0.y, b0.z, b0.w, b1.x, b1.y, b1.z, b1.w };

    f32x4 acc[8] = {};
    #pragma unroll
    for (int k = 0; k < CAP; ++k) {
        if (k < cnt) {                          // static unroll, exec-predicated
            const f32x4* row = (const f32x4*)(x + (size_t)pa[k] * CFEAT + h * 32);
            #pragma unroll
            for (int q = 0; q < 8; ++q)
                acc[q] += __builtin_nontemporal_load(row + q);
        }
    }

    if (cnt > CAP) {                            // rare slow path (~500 threads)
        int no = *ovf_cnt;
        for (int j = 0; j < no; ++j) {
            if (ovf[2 * j] == v) {
                const f32x4* row =
                    (const f32x4*)(x + (size_t)ovf[2 * j + 1] * CFEAT + h * 32);
                #pragma unroll
                for (int q = 0; q < 8; ++q)
                    acc[q] += row[q];
            }
        }
    }

    // v = (b<<16) | (ix<<8) | iy ; out flat = (b*64+c)*65536 + (v & 65535)
    // Per wave-instr: 64 consecutive iy lanes -> 256 B coalesced bursts.
    size_t base = (((size_t)(v >> 16) * CFEAT + h * 32) * (NXV * NYV))
                + (v & 65535);
    #pragma unroll
    for (int q = 0; q < 8; ++q) {
        #pragma unroll
        for (int j = 0; j < 4; ++j)
            __builtin_nontemporal_store(acc[q][j],
                out + base + (size_t)(q * 4 + j) * (NXV * NYV));
    }
}

extern "C" void kernel_launch(void* const* d_in, const int* in_sizes, int n_in,
                              void* d_out, int out_size, void* d_ws, size_t ws_size,
                              hipStream_t stream) {
    const float* x  = (const float*)d_in[0];   // fp32 [NPTS,64]
    const int* geom = (const int*)d_in[1];     // [NPTS,4]
    float* out      = (float*)d_out;           // fp32 [4,64,256,256]

    char* w = (char*)d_ws;
    int* count   = (int*)(w);
    int* ovf_cnt = (int*)(w + (1u << 20));
    int* ovf     = (int*)(w + (1u << 20) + 64);
    int* bucket  = (int*)(w + (8u << 20));

    // zero count + ovf_cnt in one memset
    hipMemsetAsync(w, 0, (1u << 20) + 64, stream);

    fill_kernel  <<<NPTS / 256, 256, 0, stream>>>(geom, count, bucket, ovf_cnt, ovf);
    gather_kernel<<<NVOX / 128, 256, 0, stream>>>(x, count, bucket, ovf_cnt, ovf, out);
}